// Round 2
// baseline (254.697 us; speedup 1.0000x reference)
//
#include <hip/hip_runtime.h>

#define NL 64
#define SQ 512
#define BATCH 1024
#define TMID 256   // forward owns t=0..255, backward owns t=511..256

typedef __fp16 hf2 __attribute__((ext_vector_type(2)));

#define EXP2F(x)  __builtin_amdgcn_exp2f(x)   // 2^x (v_exp_f32)
#define LOG2F(x)  __builtin_amdgcn_logf(x)    // log2 (v_log_f32)

__device__ __forceinline__ float lane0_bcast(float v) {
    return __uint_as_float(__builtin_amdgcn_readfirstlane(__float_as_uint(v)));
}
__device__ __forceinline__ hf2 bc2(int pki, int lane) {
    int v = __builtin_amdgcn_readlane(pki, lane);
    return __builtin_bit_cast(hf2, v);
}

// Round-8: TWO same-direction chains per wave, statically interleaved.
// Round-7 measured: step-slot 972 cyc, VALU busy 660 (= 2 waves x ~330
// issue-cyc/chain-step), ~310 cyc dependency stall that HW 2-wave
// round-robin fails to fill (L3-resident passes run at identical speed ->
// pure latency/issue bound). Fix: put both chains of a SIMD into ONE wave
// (1024 blocks, 1 wave/SIMD) and interleave A/B ops by hand:
//  - matvec2 issues readlane pairs >=4 insts ahead of their fdot2 consumers
//    (covers the VALU-write-SGPR -> VALU-read hazard),
//  - every A-chain dependency stall is filled with B-chain work statically.
// et2 (transition matrix in f16 pairs) is shared by both chains (same dir).
// Numerics are bit-identical per chain to round 7 (exponent-bit renorm,
// f16 operand window [~5e-5, ~1.4e3]).
__global__ __launch_bounds__(64, 1) void crf_scan(
    const float* __restrict__ emissions,   // [B, S, L]
    const int*   __restrict__ mask,        // [B, S]
    const float* __restrict__ trans,       // [L, L]
    const float* __restrict__ start_t,     // [L]
    const float* __restrict__ end_t,       // [L]
    float* __restrict__ ws_p,              // [2B][64]
    float* __restrict__ ws_c)              // [2B]  (log2-domain offsets)
{
    const int  blk = blockIdx.x;           // 0..1023
    const bool fwd = blk < (BATCH / 2);
    const int  bA  = fwd ? 2 * blk : 2 * (blk - BATCH / 2);
    const int  bB  = bA + 1;
    const int  j   = threadIdx.x;
    const float LOG2E = 1.44269504088896340736f;

    const float* emA = emissions + (size_t)bA * SQ * NL;
    const float* emB = emissions + (size_t)bB * SQ * NL;
    const int*   mkA = mask + (size_t)bA * SQ;
    const int*   mkB = mask + (size_t)bB * SQ;

    // ET as 32 packed f16 pairs: fwd lane j = column ET[:,j]; bwd lane i = row.
    hf2 et2[NL / 2];
#pragma unroll
    for (int k = 0; k < NL / 2; ++k) {
        float e0, e1;
        if (fwd) { e0 = __expf(trans[(2*k + 0) * NL + j]);
                   e1 = __expf(trans[(2*k + 1) * NL + j]); }
        else     { e0 = __expf(trans[j * NL + (2*k + 0)]);
                   e1 = __expf(trans[j * NL + (2*k + 1)]); }
        et2[k] = __builtin_amdgcn_cvt_pkrtz(e0, e1);
    }

    // Dual matvec: sum_i x_i * et[i] for two independent state vectors.
    // Readlanes issued >=4 insts before their consumers; A/B interleaved 1:1.
    auto matvec2 = [&](float xA, float xB, float& oA, float& oB) {
        int nA = __builtin_amdgcn_update_dpp(0, __float_as_int(xA),
                                             0xB1, 0xF, 0xF, true); // quad_perm(1,0,3,2)
        int nB = __builtin_amdgcn_update_dpp(0, __float_as_int(xB),
                                             0xB1, 0xF, 0xF, true);
        hf2 pkA = __builtin_amdgcn_cvt_pkrtz(xA, __int_as_float(nA));
        hf2 pkB = __builtin_amdgcn_cvt_pkrtz(xB, __int_as_float(nB));
        int piA = __builtin_bit_cast(int, pkA);
        int piB = __builtin_bit_cast(int, pkB);
        float a0 = 0.f, a1 = 0.f, a2 = 0.f, a3 = 0.f;
        float b0 = 0.f, b1 = 0.f, b2 = 0.f, b3 = 0.f;
#pragma unroll
        for (int k = 0; k < 32; k += 4) {
            hf2 sA0 = bc2(piA, 2*(k+0)), sB0 = bc2(piB, 2*(k+0));
            hf2 sA1 = bc2(piA, 2*(k+1)), sB1 = bc2(piB, 2*(k+1));
            hf2 sA2 = bc2(piA, 2*(k+2)), sB2 = bc2(piB, 2*(k+2));
            hf2 sA3 = bc2(piA, 2*(k+3)), sB3 = bc2(piB, 2*(k+3));
            a0 = __builtin_amdgcn_fdot2(sA0, et2[k+0], a0, false);
            b0 = __builtin_amdgcn_fdot2(sB0, et2[k+0], b0, false);
            a1 = __builtin_amdgcn_fdot2(sA1, et2[k+1], a1, false);
            b1 = __builtin_amdgcn_fdot2(sB1, et2[k+1], b1, false);
            a2 = __builtin_amdgcn_fdot2(sA2, et2[k+2], a2, false);
            b2 = __builtin_amdgcn_fdot2(sB2, et2[k+2], b2, false);
            a3 = __builtin_amdgcn_fdot2(sA3, et2[k+3], a3, false);
            b3 = __builtin_amdgcn_fdot2(sB3, et2[k+3], b3, false);
        }
        oA = (a0 + a1) + (a2 + a3);
        oB = (b0 + b1) + (b2 + b3);
    };

    float pA, pB, baseA, baseB;
    int   esumA = 0, esumB = 0;

    if (fwd) {
        auto stepPair = [&](float rA, int mA, float rB, int mB) {
            const float exA = EXP2F(rA * LOG2E);
            const float exB = EXP2F(rB * LOG2E);
            const unsigned uA = __builtin_amdgcn_readfirstlane(__float_as_uint(pA));
            const unsigned uB = __builtin_amdgcn_readfirstlane(__float_as_uint(pB));
            const int ebA = (int)((uA >> 23) & 0xffu);
            const int ebB = (int)((uB >> 23) & 0xffu);
            const float scA = __uint_as_float((unsigned)(251 - ebA) << 23); // 2^(124-eb)
            const float scB = __uint_as_float((unsigned)(251 - ebB) << 23);
            float mvA, mvB;
            matvec2(pA * scA, pB * scB, mvA, mvB);
            if (mA) { pA = exA * mvA; esumA += ebA - 124; }
            if (mB) { pB = exB * mvB; esumB += ebB - 124; }
        };

        // t = 0 init
        const float s0A = start_t[j] + emA[j];
        const float s0B = start_t[j] + emB[j];
        const float CA = lane0_bcast(s0A), CB = lane0_bcast(s0B);
        pA = EXP2F((s0A - CA) * LOG2E);  baseA = CA * LOG2E;
        pB = EXP2F((s0B - CB) * LOG2E);  baseB = CB * LOG2E;

        // peel t=1..3 + prefetch group (t=4..11) emissions + masks
        float peA1 = emA[1*NL + j], peA2 = emA[2*NL + j], peA3 = emA[3*NL + j];
        float peB1 = emB[1*NL + j], peB2 = emB[2*NL + j], peB3 = emB[3*NL + j];
        int pmA1 = mkA[1], pmA2 = mkA[2], pmA3 = mkA[3];
        int pmB1 = mkB[1], pmB2 = mkB[2], pmB3 = mkB[3];
        float rA0 = emA[ 4*NL + j], rA1 = emA[ 5*NL + j];
        float rA2 = emA[ 6*NL + j], rA3 = emA[ 7*NL + j];
        float rA4 = emA[ 8*NL + j], rA5 = emA[ 9*NL + j];
        float rA6 = emA[10*NL + j], rA7 = emA[11*NL + j];
        float rB0 = emB[ 4*NL + j], rB1 = emB[ 5*NL + j];
        float rB2 = emB[ 6*NL + j], rB3 = emB[ 7*NL + j];
        float rB4 = emB[ 8*NL + j], rB5 = emB[ 9*NL + j];
        float rB6 = emB[10*NL + j], rB7 = emB[11*NL + j];
        int4 MA0 = *reinterpret_cast<const int4*>(mkA + 4);
        int4 MA1 = *reinterpret_cast<const int4*>(mkA + 8);
        int4 MB0 = *reinterpret_cast<const int4*>(mkB + 4);
        int4 MB1 = *reinterpret_cast<const int4*>(mkB + 8);

        stepPair(peA1, pmA1, peB1, pmB1);
        stepPair(peA2, pmA2, peB2, pmB2);
        stepPair(peA3, pmA3, peB3, pmB3);

        for (int G = 0; G < 31; ++G) {                      // t = 4+8G .. 11+8G
            const int t0 = 4 + 8 * G;
            const int t8 = t0 + 8;
            const int tA = (t0+12 > 255) ? 255 : t0+12;
            const int tB = (t0+13 > 255) ? 255 : t0+13;
            const int tC = (t0+14 > 255) ? 255 : t0+14;
            const int tD = (t0+15 > 255) ? 255 : t0+15;
            float nA0 = emA[(t8+0)*NL + j], nA1 = emA[(t8+1)*NL + j];
            float nA2 = emA[(t8+2)*NL + j], nA3 = emA[(t8+3)*NL + j];
            float nA4 = emA[tA*NL + j],     nA5 = emA[tB*NL + j];
            float nA6 = emA[tC*NL + j],     nA7 = emA[tD*NL + j];
            float nB0 = emB[(t8+0)*NL + j], nB1 = emB[(t8+1)*NL + j];
            float nB2 = emB[(t8+2)*NL + j], nB3 = emB[(t8+3)*NL + j];
            float nB4 = emB[tA*NL + j],     nB5 = emB[tB*NL + j];
            float nB6 = emB[tC*NL + j],     nB7 = emB[tD*NL + j];
            const int tm1 = (t0+12 > 252) ? 252 : t0+12;    // 16B-aligned, in-bounds
            int4 nMA0 = *reinterpret_cast<const int4*>(mkA + t8);
            int4 nMA1 = *reinterpret_cast<const int4*>(mkA + tm1);
            int4 nMB0 = *reinterpret_cast<const int4*>(mkB + t8);
            int4 nMB1 = *reinterpret_cast<const int4*>(mkB + tm1);

            stepPair(rA0, MA0.x, rB0, MB0.x);
            stepPair(rA1, MA0.y, rB1, MB0.y);
            stepPair(rA2, MA0.z, rB2, MB0.z);
            stepPair(rA3, MA0.w, rB3, MB0.w);
            stepPair(rA4, MA1.x, rB4, MB1.x);
            stepPair(rA5, MA1.y, rB5, MB1.y);
            stepPair(rA6, MA1.z, rB6, MB1.z);
            stepPair(rA7, MA1.w, rB7, MB1.w);

            rA0=nA0; rA1=nA1; rA2=nA2; rA3=nA3;
            rA4=nA4; rA5=nA5; rA6=nA6; rA7=nA7;
            rB0=nB0; rB1=nB1; rB2=nB2; rB3=nB3;
            rB4=nB4; rB5=nB5; rB6=nB6; rB7=nB7;
            MA0=nMA0; MA1=nMA1; MB0=nMB0; MB1=nMB1;
        }
        // tail t=252..255
        stepPair(rA0, MA0.x, rB0, MB0.x);
        stepPair(rA1, MA0.y, rB1, MB0.y);
        stepPair(rA2, MA0.z, rB2, MB0.z);
        stepPair(rA3, MA0.w, rB3, MB0.w);
    } else {
        auto stepPair = [&](float rA, int mA, float rB, int mB) {
            const float exA = EXP2F(rA * LOG2E);
            const float exB = EXP2F(rB * LOG2E);
            const float scAv = exA * pA;                    // scale BEFORE matvec
            const float scBv = exB * pB;
            const unsigned uA = __builtin_amdgcn_readfirstlane(__float_as_uint(scAv));
            const unsigned uB = __builtin_amdgcn_readfirstlane(__float_as_uint(scBv));
            const int ebA = (int)((uA >> 23) & 0xffu);
            const int ebB = (int)((uB >> 23) & 0xffu);
            const float scA = __uint_as_float((unsigned)(251 - ebA) << 23);
            const float scB = __uint_as_float((unsigned)(251 - ebB) << 23);
            float mvA, mvB;
            matvec2(scAv * scA, scBv * scB, mvA, mvB);
            if (mA) { pA = mvA; esumA += ebA - 124; }
            if (mB) { pB = mvB; esumB += ebB - 124; }
        };

        float rA0 = emA[511*NL + j], rA1 = emA[510*NL + j];
        float rA2 = emA[509*NL + j], rA3 = emA[508*NL + j];
        float rA4 = emA[507*NL + j], rA5 = emA[506*NL + j];
        float rA6 = emA[505*NL + j], rA7 = emA[504*NL + j];
        float rB0 = emB[511*NL + j], rB1 = emB[510*NL + j];
        float rB2 = emB[509*NL + j], rB3 = emB[508*NL + j];
        float rB4 = emB[507*NL + j], rB5 = emB[506*NL + j];
        float rB6 = emB[505*NL + j], rB7 = emB[504*NL + j];
        int4 MAa = *reinterpret_cast<const int4*>(mkA + 508); // {508..511}
        int4 MAb = *reinterpret_cast<const int4*>(mkA + 504); // {504..507}
        int4 MBa = *reinterpret_cast<const int4*>(mkB + 508);
        int4 MBb = *reinterpret_cast<const int4*>(mkB + 504);

        pA = __expf(end_t[j]);  baseA = 0.f;                // q_511
        pB = pA;                baseB = 0.f;

        for (int G = 0; G < 32; ++G) {                      // t = 511-8G .. 504-8G
            const int t0 = 511 - 8 * G;
            const int tb = t0 - 8;
            const int te0 = (tb-0 < 256) ? 256 : tb-0;
            const int te1 = (tb-1 < 256) ? 256 : tb-1;
            const int te2 = (tb-2 < 256) ? 256 : tb-2;
            const int te3 = (tb-3 < 256) ? 256 : tb-3;
            const int te4 = (tb-4 < 256) ? 256 : tb-4;
            const int te5 = (tb-5 < 256) ? 256 : tb-5;
            const int te6 = (tb-6 < 256) ? 256 : tb-6;
            const int te7 = (tb-7 < 256) ? 256 : tb-7;
            float nA0 = emA[te0*NL + j], nA1 = emA[te1*NL + j];
            float nA2 = emA[te2*NL + j], nA3 = emA[te3*NL + j];
            float nA4 = emA[te4*NL + j], nA5 = emA[te5*NL + j];
            float nA6 = emA[te6*NL + j], nA7 = emA[te7*NL + j];
            float nB0 = emB[te0*NL + j], nB1 = emB[te1*NL + j];
            float nB2 = emB[te2*NL + j], nB3 = emB[te3*NL + j];
            float nB4 = emB[te4*NL + j], nB5 = emB[te5*NL + j];
            float nB6 = emB[te6*NL + j], nB7 = emB[te7*NL + j];
            const int ta  = (tb-3 < 256) ? 256 : tb-3;      // 16B-aligned
            const int tbb = (tb-7 < 256) ? 256 : tb-7;      // 16B-aligned
            int4 nMAa = *reinterpret_cast<const int4*>(mkA + ta);
            int4 nMAb = *reinterpret_cast<const int4*>(mkA + tbb);
            int4 nMBa = *reinterpret_cast<const int4*>(mkB + ta);
            int4 nMBb = *reinterpret_cast<const int4*>(mkB + tbb);

            stepPair(rA0, MAa.w, rB0, MBa.w);
            stepPair(rA1, MAa.z, rB1, MBa.z);
            stepPair(rA2, MAa.y, rB2, MBa.y);
            stepPair(rA3, MAa.x, rB3, MBa.x);
            stepPair(rA4, MAb.w, rB4, MBb.w);
            stepPair(rA5, MAb.z, rB5, MBb.z);
            stepPair(rA6, MAb.y, rB6, MBb.y);
            stepPair(rA7, MAb.x, rB7, MBb.x);

            rA0=nA0; rA1=nA1; rA2=nA2; rA3=nA3;
            rA4=nA4; rA5=nA5; rA6=nA6; rA7=nA7;
            rB0=nB0; rB1=nB1; rB2=nB2; rB3=nB3;
            rB4=nB4; rB5=nB5; rB6=nB6; rB7=nB7;
            MAa=nMAa; MAb=nMAb; MBa=nMBa; MBb=nMBb;
        }
    }

    // chain A id: fwd -> bA ; bwd -> BATCH + bA   (matches combine's layout)
    const int slotA = fwd ? bA : (BATCH + bA);
    const int slotB = slotA + 1;
    ws_p[(size_t)slotA * NL + j] = pA;
    ws_p[(size_t)slotB * NL + j] = pB;
    if (j == 0) {
        ws_c[slotA] = baseA + (float)esumA;
        ws_c[slotB] = baseB + (float)esumB;
    }
}

// out[b] = ln2 * ( c2f + c2b + log2( sum_j pf[j] * pb[j] ) )
__global__ __launch_bounds__(64) void crf_combine(
    const float* __restrict__ ws_p, const float* __restrict__ ws_c,
    float* __restrict__ out)
{
    const int b = blockIdx.x;
    const int j = threadIdx.x;
    float v = ws_p[(size_t)b * NL + j] * ws_p[(size_t)(b + BATCH) * NL + j];
#pragma unroll
    for (int off = 32; off; off >>= 1) v += __shfl_xor(v, off);
    if (j == 0)
        out[b] = 0.69314718055994530942f *
                 (ws_c[b] + ws_c[b + BATCH] + LOG2F(v));
}

extern "C" void kernel_launch(void* const* d_in, const int* in_sizes, int n_in,
                              void* d_out, int out_size, void* d_ws, size_t ws_size,
                              hipStream_t stream) {
    const float* emissions = (const float*)d_in[0];
    const int*   mask      = (const int*)d_in[1];
    const float* trans     = (const float*)d_in[2];
    const float* start_t   = (const float*)d_in[3];
    const float* end_t     = (const float*)d_in[4];
    float* out = (float*)d_out;

    float* ws_p = (float*)d_ws;                    // 2*1024*64 floats
    float* ws_c = ws_p + 2 * BATCH * NL;           // 2*1024 floats

    crf_scan<<<BATCH, NL, 0, stream>>>(emissions, mask, trans,
                                       start_t, end_t, ws_p, ws_c);
    crf_combine<<<BATCH, NL, 0, stream>>>(ws_p, ws_c, out);
}